// Round 1
// baseline (2968.952 us; speedup 1.0000x reference)
//
#include <hip/hip_runtime.h>
#include <stdint.h>

#define HDIM 512
#define NPTS 8192
#define NLAYER 16

typedef _Float16 f16;
typedef _Float16 f16x8 __attribute__((ext_vector_type(8)));
typedef _Float16 f16x4 __attribute__((ext_vector_type(4)));
typedef float    f32x4 __attribute__((ext_vector_type(4)));

__device__ __forceinline__ float sigmoid_(float x) { return 1.f / (1.f + __expf(-x)); }
__device__ __forceinline__ float tanh_(float x) {
    x = fminf(fmaxf(x, -15.f), 15.f);
    float e = __expf(2.f * x);
    return 1.f - 2.f / (e + 1.f);
}

// direct global->LDS async copy, 16B per lane (CK-style uintptr_t addrspace round-trip)
__device__ __forceinline__ void gload_lds16(const f16* g, f16* l) {
    auto* lp = reinterpret_cast<__attribute__((address_space(3))) f16*>(
        reinterpret_cast<uintptr_t>(l));
    auto* gp = reinterpret_cast<const __attribute__((address_space(1))) f16*>(
        reinterpret_cast<uintptr_t>(g));
    __builtin_amdgcn_global_load_lds(gp, lp, 16, 0, 0);
}

// ---------------- fp32 -> fp16 conversion (vectorized) ----------------
__global__ void cvt_f32_to_f16(const float* __restrict__ in, f16* __restrict__ out, int n4) {
    int i = blockIdx.x * blockDim.x + threadIdx.x;
    int stride = gridDim.x * blockDim.x;
    for (; i < n4; i += stride) {
        f32x4 v = reinterpret_cast<const f32x4*>(in)[i];
        f16x4 o;
        o[0] = (f16)v[0]; o[1] = (f16)v[1]; o[2] = (f16)v[2]; o[3] = (f16)v[3];
        reinterpret_cast<f16x4*>(out)[i] = o;
    }
}

// ---------------- weight transpose + convert: W[K][512] -> WT[512][K] fp16 ----------------
__global__ void transpose_w(const float* __restrict__ w, f16* __restrict__ wt, int K) {
    __shared__ float tile[32][33];
    int kb = blockIdx.x * 32, jb = blockIdx.y * 32;
    int tx = threadIdx.x, ty = threadIdx.y;
#pragma unroll
    for (int i = 0; i < 4; ++i)
        tile[ty + i * 8][tx] = w[(size_t)(kb + ty + i * 8) * HDIM + jb + tx];
    __syncthreads();
#pragma unroll
    for (int i = 0; i < 4; ++i)
        wt[(size_t)(jb + ty + i * 8) * K + kb + tx] = (f16)tile[tx][ty + i * 8];
}

// ---------------- fused GEMM ----------------
// C[8192 x Nout] = act( A @ W + b ), A gathered from up to 4 [8192x512] fp16 sources
// (one per 512-wide K block), W passed as W^T [Nout][K] fp16.
// MODE 0: xi-gate   (K=2048, Nout=512):  xi=sigmoid -> x0h=(1-xi)*x0, xth=xi*xl (fp16 out)
// MODE 1: u,r       (K=1536, Nout=1024): cols<512: u=sigmoid (fp32 out); cols>=512: rh=sigmoid*hx (fp16)
// MODE 2: k + blend (K=1536, Nout=512):  k=tanh; hx'=(1-u)k+u*hx -> d_out (fp32) + hx16
template <int MODE>
__global__ __launch_bounds__(128, 2) void gemm_kernel(
    const f16* __restrict__ a0, const f16* __restrict__ a1,
    const f16* __restrict__ a2, const f16* __restrict__ a3,
    const f16* __restrict__ w0, const f16* __restrict__ w1,
    const float* __restrict__ bias0, const float* __restrict__ bias1,
    const float* __restrict__ f0, const float* __restrict__ f1,
    float* __restrict__ o_f32, f16* __restrict__ o_h0, f16* __restrict__ o_h1) {
    constexpr int KDIM = (MODE == 0) ? 2048 : 1536;
    constexpr int NT = KDIM / 64;            // K-tiles of 64
    constexpr int NYV = (MODE == 1) ? 8 : 4; // grid.y
    constexpr int NWG = 128 * NYV;
    constexpr int CPX = NWG / 8;

    // [buf][ A: 64x64 | B: 128x64 ] fp16, rows of 8 16B-slots, slot XOR-swizzled by row&7
    __shared__ f16 lds[2][192 * 64];

    // bijective XCD swizzle (NWG % 8 == 0), then col-fastest so same-A-row tiles share an XCD
    int bid = blockIdx.y * 128 + blockIdx.x;
    int v = (bid & 7) * CPX + (bid >> 3);
    int rowTile = v / NYV, colTile = v % NYV;
    int row0 = rowTile * 64;
    int col0 = colTile * 128;

    const f16* wblk;
    if constexpr (MODE == 1)
        wblk = (colTile < 4) ? (w0 + (size_t)col0 * KDIM) : (w1 + (size_t)(col0 - 512) * KDIM);
    else
        wblk = w0 + (size_t)col0 * KDIM;

    const int t = threadIdx.x;
    const int lane = t & 63;
    const int wid = t >> 6;

    f32x4 acc[4][4];
#pragma unroll
    for (int m = 0; m < 4; ++m)
#pragma unroll
        for (int n = 0; n < 4; ++n)
            acc[m][n] = (f32x4){0.f, 0.f, 0.f, 0.f};

    auto stage = [&](int buf, int kt) {
        int s = kt >> 3; // which 512-wide source block
        const f16* as = (s == 0) ? a0 : (s == 1) ? a1 : (s == 2) ? a2 : a3;
        as += (size_t)row0 * HDIM + (kt & 7) * 64;
        const f16* bs = wblk + (size_t)kt * 64;
        f16* lA = &lds[buf][0];
        f16* lB = &lds[buf][4096];
        // A: 64 rows x 8 slots = 512 slots of 16B
#pragma unroll
        for (int i = 0; i < 4; ++i) {
            int d = i * 128 + t;
            int r = d >> 3, c = (d & 7) ^ (r & 7); // source k-chunk for this (linear) dest slot
            gload_lds16(as + (size_t)r * HDIM + c * 8, lA + (size_t)(i * 128 + wid * 64) * 8);
        }
        // B: 128 rows x 8 slots = 1024 slots
#pragma unroll
        for (int i = 0; i < 8; ++i) {
            int d = i * 128 + t;
            int r = d >> 3, c = (d & 7) ^ (r & 7);
            gload_lds16(bs + (size_t)r * KDIM + c * 8, lB + (size_t)(i * 128 + wid * 64) * 8);
        }
    };

    stage(0, 0);
    for (int kt = 0; kt < NT; ++kt) {
        int cur = kt & 1;
        __syncthreads(); // drains vmcnt for stage(cur); frees cur^1 for prefetch
        if (kt + 1 < NT) stage(cur ^ 1, kt + 1); // prefetch stays in flight across compute
        const f16* lA = &lds[cur][0];
        const f16* lB = &lds[cur][4096];
#pragma unroll
        for (int ks = 0; ks < 2; ++ks) { // two K=32 MFMA steps per tile
            f16x8 af[4], bf[4];
            int kc = ks * 4 + (lane >> 4); // logical 16B chunk
#pragma unroll
            for (int m = 0; m < 4; ++m) {
                int r = m * 16 + (lane & 15);
                af[m] = *(const f16x8*)(lA + r * 64 + ((kc ^ (r & 7)) * 8));
            }
#pragma unroll
            for (int n = 0; n < 4; ++n) {
                int r = wid * 64 + n * 16 + (lane & 15);
                bf[n] = *(const f16x8*)(lB + r * 64 + ((kc ^ (r & 7)) * 8));
            }
#pragma unroll
            for (int m = 0; m < 4; ++m)
#pragma unroll
                for (int n = 0; n < 4; ++n)
                    acc[m][n] = __builtin_amdgcn_mfma_f32_16x16x32_f16(af[m], bf[n], acc[m][n], 0, 0, 0);
        }
    }

    // epilogue: C/D layout col=lane&15, row=(lane>>4)*4+i
#pragma unroll
    for (int n = 0; n < 4; ++n) {
        int j = col0 + wid * 64 + n * 16 + (lane & 15);
#pragma unroll
        for (int m = 0; m < 4; ++m) {
            int rbase = row0 + m * 16 + ((lane >> 4) << 2);
#pragma unroll
            for (int i = 0; i < 4; ++i) {
                int row = rbase + i;
                float pre = acc[m][n][i];
                if constexpr (MODE == 0) {
                    float xi = sigmoid_(pre + bias0[j]);
                    size_t idx = (size_t)row * HDIM + j;
                    o_h0[idx] = (f16)((1.f - xi) * f0[idx]); // x0_h
                    o_h1[idx] = (f16)(xi * f1[idx]);         // xt_h
                } else if constexpr (MODE == 1) {
                    if (colTile < 4) {
                        float u = sigmoid_(pre + bias0[j]);
                        o_f32[(size_t)row * HDIM + j] = u;
                    } else {
                        int j2 = j - 512;
                        float r = sigmoid_(pre + bias1[j2]);
                        size_t idx = (size_t)row * HDIM + j2;
                        o_h0[idx] = (f16)(r * f0[idx]); // r*hx
                    }
                } else {
                    float kk = tanh_(pre + bias0[j]);
                    size_t idx = (size_t)row * HDIM + j;
                    float u = f0[idx];
                    float hxo = o_f32[idx];
                    float hxn = (1.f - u) * kk + u * hxo;
                    o_f32[idx] = hxn;        // hx fp32 (d_out)
                    o_h0[idx] = (f16)hxn;    // hx fp16
                }
            }
        }
    }
}

extern "C" void kernel_launch(void* const* d_in, const int* in_sizes, int n_in,
                              void* d_out, int out_size, void* d_ws, size_t ws_size,
                              hipStream_t stream) {
    (void)in_sizes; (void)n_in; (void)out_size; (void)ws_size;
    constexpr size_t NH = (size_t)NPTS * HDIM;

    const float* ef = (const float*)d_in[0];
    const float* nf = (const float*)d_in[1];
    const float* Wxi = (const float*)d_in[2];
    const float* bxi = (const float*)d_in[3];
    const float* Wu = (const float*)d_in[4];
    const float* bu = (const float*)d_in[5];
    const float* Wr = (const float*)d_in[6];
    const float* br = (const float*)d_in[7];
    const float* Wk = (const float*)d_in[8];
    const float* bk = (const float*)d_in[9];
    float* hxf = (float*)d_out;

    char* w = (char*)d_ws;
    f16* x016 = (f16*)w; w += NH * 2;
    f16* el16 = (f16*)w; w += NH * 2;
    f16* xl16 = (f16*)w; w += NH * 2;
    f16* hx16 = (f16*)w; w += NH * 2;
    f16* x0h16 = (f16*)w; w += NH * 2;
    f16* xth16 = (f16*)w; w += NH * 2;
    f16* rh16 = (f16*)w; w += NH * 2;
    float* uf = (float*)w; w += NH * 4;
    f16* WxiT = (f16*)w; w += (size_t)512 * 2048 * 2;
    f16* WuT = (f16*)w; w += (size_t)512 * 1536 * 2;
    f16* WrT = (f16*)w; w += (size_t)512 * 1536 * 2;
    f16* WkT = (f16*)w; w += (size_t)512 * 1536 * 2;

    // hx0 = 0 (both precisions); d_out/d_ws are poisoned before every launch
    hipMemsetAsync(hx16, 0, NH * 2, stream);
    hipMemsetAsync(hxf, 0, NH * 4, stream);

    cvt_f32_to_f16<<<2048, 256, 0, stream>>>(nf + (size_t)NLAYER * NH, x016, (int)(NH / 4));
    transpose_w<<<dim3(64, 16), dim3(32, 8), 0, stream>>>(Wxi, WxiT, 2048);
    transpose_w<<<dim3(48, 16), dim3(32, 8), 0, stream>>>(Wu, WuT, 1536);
    transpose_w<<<dim3(48, 16), dim3(32, 8), 0, stream>>>(Wr, WrT, 1536);
    transpose_w<<<dim3(48, 16), dim3(32, 8), 0, stream>>>(Wk, WkT, 1536);

    for (int l = 0; l < NLAYER; ++l) {
        cvt_f32_to_f16<<<2048, 256, 0, stream>>>(ef + (size_t)l * NH, el16, (int)(NH / 4));
        cvt_f32_to_f16<<<2048, 256, 0, stream>>>(nf + (size_t)l * NH, xl16, (int)(NH / 4));
        // xi gate: A = [hx | el | x0 | xl]
        gemm_kernel<0><<<dim3(128, 4), 128, 0, stream>>>(
            hx16, el16, x016, xl16, WxiT, nullptr, bxi, nullptr,
            nf + (size_t)NLAYER * NH, nf + (size_t)l * NH, nullptr, x0h16, xth16);
        // u, r: A = [hx | x0_h | xt_h], B = [W_u | W_r]
        gemm_kernel<1><<<dim3(128, 8), 128, 0, stream>>>(
            hx16, x0h16, xth16, nullptr, WuT, WrT, bu, br,
            hxf, nullptr, uf, rh16, nullptr);
        // k + hx update: A = [x0_h | xt_h | r*hx]
        gemm_kernel<2><<<dim3(128, 4), 128, 0, stream>>>(
            x0h16, xth16, rh16, nullptr, WkT, nullptr, bk, nullptr,
            uf, nullptr, hxf, hx16, nullptr);
    }
}

// Round 4
// 2319.797 us; speedup vs baseline: 1.2798x; 1.2798x over previous
//
#include <hip/hip_runtime.h>
#include <stdint.h>

#define HDIM 512
#define NPTS 8192
#define NLAYER 16

typedef _Float16 f16;
typedef _Float16 f16x8 __attribute__((ext_vector_type(8)));
typedef _Float16 f16x4 __attribute__((ext_vector_type(4)));
typedef float    f32x4 __attribute__((ext_vector_type(4)));

__device__ __forceinline__ float sigmoid_(float x) { return 1.f / (1.f + __expf(-x)); }
__device__ __forceinline__ float tanh_(float x) {
    x = fminf(fmaxf(x, -15.f), 15.f);
    float e = __expf(2.f * x);
    return 1.f - 2.f / (e + 1.f);
}

// direct global->LDS async copy, 16B per lane (wave-uniform LDS base + lane*16)
__device__ __forceinline__ void gload_lds16(const f16* g, f16* l) {
    auto* lp = reinterpret_cast<__attribute__((address_space(3))) f16*>(
        reinterpret_cast<uintptr_t>(l));
    auto* gp = reinterpret_cast<const __attribute__((address_space(1))) f16*>(
        reinterpret_cast<uintptr_t>(g));
    __builtin_amdgcn_global_load_lds(gp, lp, 16, 0, 0);
}

// ---------------- fp32 -> fp16 conversion (vectorized, grid-stride) ----------------
__global__ void cvt_f32_to_f16(const float* __restrict__ in, f16* __restrict__ out, int n4) {
    int i = blockIdx.x * blockDim.x + threadIdx.x;
    int stride = gridDim.x * blockDim.x;
    for (; i < n4; i += stride) {
        f32x4 v = reinterpret_cast<const f32x4*>(in)[i];
        f16x4 o;
        o[0] = (f16)v[0]; o[1] = (f16)v[1]; o[2] = (f16)v[2]; o[3] = (f16)v[3];
        reinterpret_cast<f16x4*>(out)[i] = o;
    }
}

// ---------------- weight transpose + convert: W[K][512] -> WT[512][K] fp16 ----------------
__global__ void transpose_w(const float* __restrict__ w, f16* __restrict__ wt, int K) {
    __shared__ float tile[32][33];
    int kb = blockIdx.x * 32, jb = blockIdx.y * 32;
    int tx = threadIdx.x, ty = threadIdx.y;
#pragma unroll
    for (int i = 0; i < 4; ++i)
        tile[ty + i * 8][tx] = w[(size_t)(kb + ty + i * 8) * HDIM + jb + tx];
    __syncthreads();
#pragma unroll
    for (int i = 0; i < 4; ++i)
        wt[(size_t)(jb + ty + i * 8) * K + kb + tx] = (f16)tile[tx][ty + i * 8];
}

// ---------------- fused GEMM ----------------
// C[8192 x Nout] = act( A @ W + b ), A gathered from up to 4 [8192x512] fp16 sources
// (one per 512-wide K block), W passed as W^T [Nout][K] fp16.
// Block: BM=64 x BN=128, 256 threads = 4 waves, wave-tile 64x32 (8 waves/CU = 2/SIMD).
// MODE 0: xi  (K=2048, Nout=512):  xi=sigmoid -> x0h=(1-xi)*x0 (g0), xth=xi*xl (g1), fp16 out
// MODE 1: u,r (K=1536, Nout=1024): cols<512: u=sigmoid (fp16 -> o_h1); cols>=512: rh=sigmoid*hx(g0) -> o_h0
// MODE 2: k   (K=1536, Nout=512):  k=tanh; hx'=(1-u(g0))k+u*hx -> o_f32 (d_out) + o_h0 fp16
template <int MODE>
__global__ __launch_bounds__(256, 2) void gemm_kernel(
    const f16* __restrict__ a0, const f16* __restrict__ a1,
    const f16* __restrict__ a2, const f16* __restrict__ a3,
    const f16* __restrict__ w0, const f16* __restrict__ w1,
    const float* __restrict__ bias0, const float* __restrict__ bias1,
    const f16* __restrict__ g0, const f16* __restrict__ g1,
    float* __restrict__ o_f32, f16* __restrict__ o_h0, f16* __restrict__ o_h1) {
    constexpr int KDIM = (MODE == 0) ? 2048 : 1536;
    constexpr int NT = KDIM / 64;            // K-tiles of 64
    constexpr int NYV = (MODE == 1) ? 8 : 4; // column tiles (BN=128)
    constexpr int NWG = 128 * NYV;
    constexpr int CPX = NWG / 8;

    // [buf][ A: 64x64 | B: 128x64 ] fp16, rows of 8 16B-slots, slot XOR-swizzled by row&7
    __shared__ f16 lds[2][192 * 64];

    // bijective XCD swizzle (NWG % 8 == 0); consecutive v share rowTile -> A L2 locality
    int bid = blockIdx.y * 128 + blockIdx.x;
    int v = (bid & 7) * CPX + (bid >> 3);
    int rowTile = v / NYV, colTile = v % NYV;
    int row0 = rowTile * 64;
    int col0 = colTile * 128;

    const f16* wblk;
    if constexpr (MODE == 1)
        wblk = (colTile < 4) ? (w0 + (size_t)col0 * KDIM) : (w1 + (size_t)(col0 - 512) * KDIM);
    else
        wblk = w0 + (size_t)col0 * KDIM;

    const int t = threadIdx.x;
    const int lane = t & 63;
    const int wid = t >> 6;

    f32x4 acc[4][2];
#pragma unroll
    for (int m = 0; m < 4; ++m)
#pragma unroll
        for (int n = 0; n < 2; ++n)
            acc[m][n] = (f32x4){0.f, 0.f, 0.f, 0.f};

    auto stage = [&](int buf, int kt) {
        int s = kt >> 3; // which 512-wide source block
        const f16* as = (s == 0) ? a0 : (s == 1) ? a1 : (s == 2) ? a2 : a3;
        as += (size_t)row0 * HDIM + (kt & 7) * 64;
        const f16* bs = wblk + (size_t)kt * 64;
        f16* lA = &lds[buf][0];
        f16* lB = &lds[buf][4096];
        // A: 64 rows x 8 slots = 512 slots of 16B; 2 iters of 256 threads
#pragma unroll
        for (int i = 0; i < 2; ++i) {
            int d = i * 256 + t;
            int r = d >> 3, c = (d & 7) ^ (r & 7); // inverse-swizzled global source
            gload_lds16(as + (size_t)r * HDIM + c * 8, lA + (size_t)(i * 256 + wid * 64) * 8);
        }
        // B: 128 rows x 8 slots = 1024 slots; 4 iters
#pragma unroll
        for (int i = 0; i < 4; ++i) {
            int d = i * 256 + t;
            int r = d >> 3, c = (d & 7) ^ (r & 7);
            gload_lds16(bs + (size_t)r * KDIM + c * 8, lB + (size_t)(i * 256 + wid * 64) * 8);
        }
    };

    stage(0, 0);
    for (int kt = 0; kt < NT; ++kt) {
        int cur = kt & 1;
        __syncthreads(); // drains stage(cur); prefetch below stays in flight over compute
        if (kt + 1 < NT) stage(cur ^ 1, kt + 1);
        const f16* lA = &lds[cur][0];
        const f16* lB = &lds[cur][4096];
#pragma unroll
        for (int ks = 0; ks < 2; ++ks) { // two K=32 MFMA steps per tile
            f16x8 af[4], bf[2];
            int kc = ks * 4 + (lane >> 4); // logical 16B chunk
#pragma unroll
            for (int m = 0; m < 4; ++m) {
                int r = m * 16 + (lane & 15);
                af[m] = *(const f16x8*)(lA + r * 64 + ((kc ^ (r & 7)) * 8));
            }
#pragma unroll
            for (int n = 0; n < 2; ++n) {
                int r = wid * 32 + n * 16 + (lane & 15);
                bf[n] = *(const f16x8*)(lB + r * 64 + ((kc ^ (r & 7)) * 8));
            }
#pragma unroll
            for (int m = 0; m < 4; ++m)
#pragma unroll
                for (int n = 0; n < 2; ++n)
                    acc[m][n] = __builtin_amdgcn_mfma_f32_16x16x32_f16(af[m], bf[n], acc[m][n], 0, 0, 0);
        }
    }

    // epilogue: C/D layout col=lane&15, row=(lane>>4)*4+i
#pragma unroll
    for (int n = 0; n < 2; ++n) {
        int j = col0 + wid * 32 + n * 16 + (lane & 15);
#pragma unroll
        for (int m = 0; m < 4; ++m) {
            int rbase = row0 + m * 16 + ((lane >> 4) << 2);
#pragma unroll
            for (int i = 0; i < 4; ++i) {
                int row = rbase + i;
                float pre = acc[m][n][i];
                if constexpr (MODE == 0) {
                    float xi = sigmoid_(pre + bias0[j]);
                    size_t idx = (size_t)row * HDIM + j;
                    o_h0[idx] = (f16)((1.f - xi) * (float)g0[idx]); // x0_h
                    o_h1[idx] = (f16)(xi * (float)g1[idx]);         // xt_h
                } else if constexpr (MODE == 1) {
                    if (colTile < 4) {
                        float u = sigmoid_(pre + bias0[j]);
                        o_h1[(size_t)row * HDIM + j] = (f16)u;
                    } else {
                        int j2 = j - 512;
                        float r = sigmoid_(pre + bias1[j2]);
                        size_t idx = (size_t)row * HDIM + j2;
                        o_h0[idx] = (f16)(r * (float)g0[idx]); // r*hx
                    }
                } else {
                    float kk = tanh_(pre + bias0[j]);
                    size_t idx = (size_t)row * HDIM + j;
                    float u = (float)g0[idx];
                    float hxo = o_f32[idx];
                    float hxn = (1.f - u) * kk + u * hxo;
                    o_f32[idx] = hxn;     // hx fp32 (d_out)
                    o_h0[idx] = (f16)hxn; // hx fp16 (next layer's A operand)
                }
            }
        }
    }
}

extern "C" void kernel_launch(void* const* d_in, const int* in_sizes, int n_in,
                              void* d_out, int out_size, void* d_ws, size_t ws_size,
                              hipStream_t stream) {
    (void)in_sizes; (void)n_in; (void)out_size; (void)ws_size;
    constexpr size_t NH = (size_t)NPTS * HDIM;

    const float* ef = (const float*)d_in[0];
    const float* nf = (const float*)d_in[1];
    const float* Wxi = (const float*)d_in[2];
    const float* bxi = (const float*)d_in[3];
    const float* Wu = (const float*)d_in[4];
    const float* bu = (const float*)d_in[5];
    const float* Wr = (const float*)d_in[6];
    const float* br = (const float*)d_in[7];
    const float* Wk = (const float*)d_in[8];
    const float* bk = (const float*)d_in[9];
    float* hxf = (float*)d_out;

    char* w = (char*)d_ws;
    f16* ef16 = (f16*)w; w += (size_t)NLAYER * NH * 2;       // 16 layers of edge feats
    f16* nf16 = (f16*)w; w += (size_t)(NLAYER + 1) * NH * 2; // 17 slabs (incl. x0)
    f16* hx16 = (f16*)w; w += NH * 2;
    f16* x0h16 = (f16*)w; w += NH * 2;
    f16* xth16 = (f16*)w; w += NH * 2;
    f16* rh16 = (f16*)w; w += NH * 2;
    f16* u16 = (f16*)w; w += NH * 2;
    f16* WxiT = (f16*)w; w += (size_t)512 * 2048 * 2;
    f16* WuT = (f16*)w; w += (size_t)512 * 1536 * 2;
    f16* WrT = (f16*)w; w += (size_t)512 * 1536 * 2;
    f16* WkT = (f16*)w; w += (size_t)512 * 1536 * 2;

    const f16* x016 = nf16 + (size_t)NLAYER * NH;

    // hx0 = 0 (ws/out are re-poisoned before every launch, so do this every call)
    hipMemsetAsync(hx16, 0, NH * 2, stream);
    hipMemsetAsync(hxf, 0, NH * 4, stream);

    // upfront bulk conversions (2 kernels instead of 32 per-layer ones)
    cvt_f32_to_f16<<<2048, 256, 0, stream>>>(ef, ef16, (int)(NLAYER * NH / 4));
    cvt_f32_to_f16<<<2048, 256, 0, stream>>>(nf, nf16, (int)((NLAYER + 1) * NH / 4));
    transpose_w<<<dim3(64, 16), dim3(32, 8), 0, stream>>>(Wxi, WxiT, 2048);
    transpose_w<<<dim3(48, 16), dim3(32, 8), 0, stream>>>(Wu, WuT, 1536);
    transpose_w<<<dim3(48, 16), dim3(32, 8), 0, stream>>>(Wr, WrT, 1536);
    transpose_w<<<dim3(48, 16), dim3(32, 8), 0, stream>>>(Wk, WkT, 1536);

    for (int l = 0; l < NLAYER; ++l) {
        const f16* el16 = ef16 + (size_t)l * NH;
        const f16* xl16 = nf16 + (size_t)l * NH;
        // xi gate: A = [hx | el | x0 | xl]
        gemm_kernel<0><<<dim3(128, 4), 256, 0, stream>>>(
            hx16, el16, x016, xl16, WxiT, nullptr, bxi, nullptr,
            x016, xl16, nullptr, x0h16, xth16);
        // u, r: A = [hx | x0_h | xt_h], B = [W_u | W_r]
        gemm_kernel<1><<<dim3(128, 8), 256, 0, stream>>>(
            hx16, x0h16, xth16, nullptr, WuT, WrT, bu, br,
            hx16, nullptr, nullptr, rh16, u16);
        // k + hx update: A = [x0_h | xt_h | r*hx]
        gemm_kernel<2><<<dim3(128, 4), 256, 0, stream>>>(
            x0h16, xth16, rh16, nullptr, WkT, nullptr, bk, nullptr,
            u16, nullptr, hxf, hx16, nullptr);
    }
}